// Round 1
// baseline (519.054 us; speedup 1.0000x reference)
//
#include <hip/hip_runtime.h>
#include <hip/hip_bf16.h>

#define NB 2
#define NC 16
#define NN 8192
#define NBC 32   // NB*NC columns of the skinny GEMM
#define KS 4     // K-split factor

typedef float f32x4 __attribute__((ext_vector_type(4)));
typedef __bf16 bf16x8 __attribute__((ext_vector_type(8)));

// ---------------- GroupNorm stats: one block per (b,g), 16 blocks ----------------
__global__ void gn_stats_k(const float* __restrict__ c, float* __restrict__ stats) {
    int bg = blockIdx.x;                       // b*8 + g
    const float* p = c + (size_t)bg * 16384;   // channels 2g,2g+1 are contiguous rows
    float s = 0.f, ss = 0.f;
    for (int i = threadIdx.x; i < 4096; i += 256) {
        float4 v = ((const float4*)p)[i];
        s  += v.x + v.y + v.z + v.w;
        ss += v.x*v.x + v.y*v.y + v.z*v.z + v.w*v.w;
    }
    #pragma unroll
    for (int o = 32; o; o >>= 1) { s += __shfl_down(s, o); ss += __shfl_down(ss, o); }
    __shared__ float sh[8];
    int w = threadIdx.x >> 6;
    if ((threadIdx.x & 63) == 0) { sh[w] = s; sh[w + 4] = ss; }
    __syncthreads();
    if (threadIdx.x == 0) {
        float S = sh[0]+sh[1]+sh[2]+sh[3], SS = sh[4]+sh[5]+sh[6]+sh[7];
        float mu = S * (1.f/16384.f);
        float var = SS * (1.f/16384.f) - mu*mu;
        stats[bg*2]   = mu;
        stats[bg*2+1] = rsqrtf(var + 1e-5f);
    }
}

// ---------------- y = GN(c)^T, x0 = normalize(x^T); write f32 state + bf16 X ----------------
__global__ void prep_xy_k(const float* __restrict__ x, const float* __restrict__ c,
                          const float* __restrict__ gnw, const float* __restrict__ gnb,
                          const float* __restrict__ stats,
                          float* __restrict__ y_arr, float* __restrict__ x0f,
                          __bf16* __restrict__ Xbf) {
    int tid = blockIdx.x * 256 + threadIdx.x;  // 131072 = B*N*8
    int n = tid & (NN - 1);
    int j = (tid >> 13) & 7;
    int b = tid >> 16;
    int ch0 = 2 * j;
    size_t r0 = ((size_t)(b * NC + ch0)) * NN + n;
    float c0 = c[r0], c1 = c[r0 + NN];
    float x0 = x[r0], x1 = x[r0 + NN];
    float mu = stats[(b*8 + j)*2], rstd = stats[(b*8 + j)*2 + 1];
    float y0 = (c0 - mu) * rstd * gnw[ch0]   + gnb[ch0];
    float y1 = (c1 - mu) * rstd * gnw[ch0+1] + gnb[ch0+1];
    int base = n * NBC + b * NC + ch0;
    y_arr[base] = y0; y_arr[base + 1] = y1;
    float inv = 1.f / (sqrtf(x0*x0 + x1*x1) + 1e-6f);
    x0 *= inv; x1 *= inv;
    size_t xi = ((size_t)(b * NN + n)) * NC + ch0;
    x0f[xi] = x0; x0f[xi + 1] = x1;
    Xbf[(size_t)(b*NC + ch0)     * NN + n] = (__bf16)x0;
    Xbf[(size_t)(b*NC + ch0 + 1) * NN + n] = (__bf16)x1;
}

// ---------------- A = bf16(sc * conn_w), 8 elems/thread ----------------
__global__ void prep_A_k(const float* __restrict__ sc, const float* __restrict__ cw,
                         __bf16* __restrict__ Abf) {
    size_t i = ((size_t)blockIdx.x * 256 + threadIdx.x) * 8;
    float4 s0 = ((const float4*)(sc + i))[0], s1 = ((const float4*)(sc + i))[1];
    float4 w0 = ((const float4*)(cw + i))[0], w1 = ((const float4*)(cw + i))[1];
    bf16x8 o;
    o[0]=(__bf16)(s0.x*w0.x); o[1]=(__bf16)(s0.y*w0.y);
    o[2]=(__bf16)(s0.z*w0.z); o[3]=(__bf16)(s0.w*w0.w);
    o[4]=(__bf16)(s1.x*w1.x); o[5]=(__bf16)(s1.y*w1.y);
    o[6]=(__bf16)(s1.z*w1.z); o[7]=(__bf16)(s1.w*w1.w);
    *(bf16x8*)(Abf + i) = o;
}

__device__ inline bf16x8 mulcvt8(const float* __restrict__ s, const float* __restrict__ w) {
    float4 s0 = ((const float4*)s)[0], s1 = ((const float4*)s)[1];
    float4 w0 = ((const float4*)w)[0], w1 = ((const float4*)w)[1];
    bf16x8 r;
    r[0]=(__bf16)(s0.x*w0.x); r[1]=(__bf16)(s0.y*w0.y);
    r[2]=(__bf16)(s0.z*w0.z); r[3]=(__bf16)(s0.w*w0.w);
    r[4]=(__bf16)(s1.x*w1.x); r[5]=(__bf16)(s1.y*w1.y);
    r[6]=(__bf16)(s1.z*w1.z); r[7]=(__bf16)(s1.w*w1.w);
    return r;
}

// ---------------- coup partials = A(chunk) @ X : grid (128 m-blocks, KS) ----------------
// wave w: rows [mb*64 + w*16, +16) x all 32 cols; direct global->fragment loads.
template<bool FUSED>
__global__ __launch_bounds__(256) void gemm_step_k(const __bf16* __restrict__ Abf,
                                                   const float* __restrict__ sc,
                                                   const float* __restrict__ cw,
                                                   const __bf16* __restrict__ Xbf,
                                                   float* __restrict__ part) {
    int mb = blockIdx.x;
    int ks = blockIdx.y;
    int lane = threadIdx.x & 63;
    int w = threadIdx.x >> 6;
    int row = mb * 64 + w * 16 + (lane & 15);
    int kb  = (lane >> 4) * 8;
    int k0  = ks * (NN / KS);
    f32x4 acc0 = {0.f,0.f,0.f,0.f}, acc1 = {0.f,0.f,0.f,0.f};
    const __bf16* bp0 = Xbf + (size_t)(lane & 15) * NN + k0 + kb;
    const __bf16* bp1 = bp0 + (size_t)16 * NN;
    if (FUSED) {
        const float* as = sc + (size_t)row * NN + k0 + kb;
        const float* aw = cw + (size_t)row * NN + k0 + kb;
        #pragma unroll 4
        for (int k = 0; k < NN / KS; k += 32) {
            bf16x8 a  = mulcvt8(as + k, aw + k);
            bf16x8 b0 = *(const bf16x8*)(bp0 + k);
            bf16x8 b1 = *(const bf16x8*)(bp1 + k);
            acc0 = __builtin_amdgcn_mfma_f32_16x16x32_bf16(a, b0, acc0, 0, 0, 0);
            acc1 = __builtin_amdgcn_mfma_f32_16x16x32_bf16(a, b1, acc1, 0, 0, 0);
        }
    } else {
        const __bf16* ap = Abf + (size_t)row * NN + k0 + kb;
        #pragma unroll 8
        for (int k = 0; k < NN / KS; k += 32) {
            bf16x8 a  = *(const bf16x8*)(ap + k);
            bf16x8 b0 = *(const bf16x8*)(bp0 + k);
            bf16x8 b1 = *(const bf16x8*)(bp1 + k);
            acc0 = __builtin_amdgcn_mfma_f32_16x16x32_bf16(a, b0, acc0, 0, 0, 0);
            acc1 = __builtin_amdgcn_mfma_f32_16x16x32_bf16(a, b1, acc1, 0, 0, 0);
        }
    }
    // C/D layout: col = lane&15, row = (lane>>4)*4 + r  [HW-verified]
    int orow = mb * 64 + w * 16 + (lane >> 4) * 4;
    int ocol = lane & 15;
    float* pp = part + (size_t)ks * NN * NBC + (size_t)orow * NBC + ocol;
    #pragma unroll
    for (int r = 0; r < 4; ++r) {
        pp[(size_t)r * NBC]      = acc0[r];
        pp[(size_t)r * NBC + 16] = acc1[r];
    }
}

// ---------------- oscillator update: one thread per (b, n, pair j) ----------------
__global__ void update_step_k(const float* __restrict__ part, const float* __restrict__ y_arr,
                              const float* __restrict__ omg, const float* __restrict__ gamma,
                              float* __restrict__ x0f, __bf16* __restrict__ Xbf,
                              float* __restrict__ out_k) {
    int tid = blockIdx.x * 256 + threadIdx.x;   // 131072
    int j = tid & 7;
    int n = (tid >> 3) & (NN - 1);
    int b = tid >> 16;
    int base = n * NBC + b * NC + 2 * j;
    float c0 = 0.f, c1 = 0.f;
    #pragma unroll
    for (int ks = 0; ks < KS; ++ks) {
        const float* p = part + (size_t)ks * NN * NBC + base;
        c0 += p[0]; c1 += p[1];
    }
    float y0 = y_arr[base] + c0;
    float y1 = y_arr[base + 1] + c1;
    size_t xi = ((size_t)(b * NN + n)) * NC + 2 * j;
    float x0 = x0f[xi], x1 = x0f[xi + 1];
    float sim = x0 * y0 + x1 * y1;
    float p0 = y0 - sim * x0;
    float p1 = y1 - sim * x1;
    float om = fabsf(omg[j]);
    float g  = gamma[0];
    float v0 = x0 + g * ( om * x1 + p0);
    float v1 = x1 + g * (-om * x0 + p1);
    float inv = 1.f / (sqrtf(v0*v0 + v1*v1) + 1e-6f);
    v0 *= inv; v1 *= inv;
    out_k[xi] = v0; out_k[xi + 1] = v1;
    x0f[xi] = v0; x0f[xi + 1] = v1;
    Xbf[(size_t)(b*NC + 2*j)     * NN + n] = (__bf16)v0;
    Xbf[(size_t)(b*NC + 2*j + 1) * NN + n] = (__bf16)v1;
}

extern "C" void kernel_launch(void* const* d_in, const int* in_sizes, int n_in,
                              void* d_out, int out_size, void* d_ws, size_t ws_size,
                              hipStream_t stream) {
    const float* x     = (const float*)d_in[0];
    const float* c     = (const float*)d_in[1];
    const float* sc    = (const float*)d_in[2];
    const float* gnw   = (const float*)d_in[3];
    const float* gnb   = (const float*)d_in[4];
    const float* cw    = (const float*)d_in[5];
    const float* omg   = (const float*)d_in[6];
    const float* gamma = (const float*)d_in[7];
    float* out = (float*)d_out;
    int Q = out_size / (NB * NN * NC);

    const size_t szA = (size_t)NN * NN * 2;          // 128 MiB
    const size_t szXbf = (size_t)NBC * NN * 2;       // 512 KiB
    const size_t szX0f = (size_t)NB * NN * NC * 4;   // 1 MiB
    const size_t szY   = (size_t)NN * NBC * 4;       // 1 MiB
    const size_t szPart = (size_t)KS * NN * NBC * 4; // 4 MiB
    const size_t rest = szXbf + szX0f + szY + szPart + 256;
    bool bigws = ws_size >= szA + rest;

    char* p = (char*)d_ws;
    __bf16* Abf = nullptr;
    if (bigws) { Abf = (__bf16*)p; p += szA; }
    __bf16* Xbf  = (__bf16*)p; p += szXbf;
    float* x0f   = (float*)p;  p += szX0f;
    float* y_arr = (float*)p;  p += szY;
    float* part  = (float*)p;  p += szPart;
    float* stats = (float*)p;  p += 256;

    gn_stats_k<<<16, 256, 0, stream>>>(c, stats);
    prep_xy_k<<<(NB * NN * 8) / 256, 256, 0, stream>>>(x, c, gnw, gnb, stats, y_arr, x0f, Xbf);
    if (bigws)
        prep_A_k<<<((size_t)NN * NN / 8) / 256, 256, 0, stream>>>(sc, cw, Abf);

    dim3 gg(NN / 64, KS);
    for (int k = 0; k < Q; ++k) {
        if (bigws)
            gemm_step_k<false><<<gg, 256, 0, stream>>>(Abf, sc, cw, Xbf, part);
        else
            gemm_step_k<true><<<gg, 256, 0, stream>>>(nullptr, sc, cw, Xbf, part);
        update_step_k<<<(NB * NN * 8) / 256, 256, 0, stream>>>(
            part, y_arr, omg, gamma, x0f, Xbf, out + (size_t)k * NB * NN * NC);
    }
}